// Round 3
// baseline (234.099 us; speedup 1.0000x reference)
//
#include <hip/hip_runtime.h>

#define BZ    167              // grid3d_index dims 0/1 (SIZE + 2*MARGIN)
#define BZ2   83               // BZ/2
#define NX    84               // BZ/2 + 1  (last axis)
#define NCELL (BZ * BZ * NX)   // 2,342,676 cells
#define NBX   51               // ceil(13041/256) blocks/batch (fallback tiers)
#define NBP2  51               // ceil(13041/256) blocks/batch (2-pt quad kernel)

// ---- bf16 helpers (round-to-nearest-even pack, free unpack) ----
static __device__ __forceinline__ unsigned f2bf(float f) {
    unsigned u = __float_as_uint(f);
    return (u + 0x7FFFu + ((u >> 16) & 1u)) >> 16;
}
static __device__ __forceinline__ float bf_lo(unsigned u) {
    return __uint_as_float(u << 16);
}
static __device__ __forceinline__ float bf_hi(unsigned u) {
    return __uint_as_float(u & 0xFFFF0000u);
}

// ---- fused pre-pass: pack weights fp32->bf16 (coalesced float4->uint2) AND
// build garr[cell] = (j, bias bf16x2) in one dispatch ----
__global__ __launch_bounds__(256) void pack_all(
    const float4* __restrict__ wsrc, uint2* __restrict__ wdst, int nw4, int nbw,
    const int* __restrict__ grid, const float* __restrict__ bias,
    int2* __restrict__ garr, int ncell)
{
    if ((int)blockIdx.x < nbw) {
        const int i = blockIdx.x * 256 + threadIdx.x;
        if (i >= nw4) return;
        const float4 v = wsrc[i];
        wdst[i] = make_uint2(f2bf(v.x) | (f2bf(v.y) << 16),
                             f2bf(v.z) | (f2bf(v.w) << 16));
    } else {
        const int i = ((int)blockIdx.x - nbw) * 256 + threadIdx.x;
        if (i >= ncell) return;
        const int j = grid[i];
        unsigned bb = 0u;
        if (j >= 0)
            bb = f2bf(bias[2 * j]) | (f2bf(bias[2 * j + 1]) << 16);
        garr[i] = make_int2(j, (int)bb);
    }
}

// ========= main kernel: quarter-lane, TWO points per thread ==================
// Diagnosis R0-R2: dur pinned ~100us across traffic 278-294MB and VALU 48-67us
// -> gather-LATENCY bound (2 dependent L3-hit rounds/point), constrained by
// concurrency = waves/CU x chains/wave. This version raises both:
//   * 512-thread blocks + __launch_bounds__(512,8) -> 4 blocks/CU = 32
//     waves/CU (occupancy 72% -> ~100%), grid 209k -> 13k blocks
//   * each thread runs points A (p) and B (p+128): both garr rounds issue
//     before either wpk round -> 2 interleaved chains, 16 loads in flight
// Invalid points take a uniform clamped-to-center path (weights forced 0,
// gathers hit one L2-hot line) so mixed waves never diverge; fully-dead waves
// exit via one wave-uniform __any.
__global__ __launch_bounds__(512, 8) void svr_quad2(
    const float*    __restrict__ input,   // (B, 8)
    const unsigned* __restrict__ wpk,     // (W, 8) uints = 16 bf16
    const int2*     __restrict__ garr,    // (NCELL): (j, bias bf16x2)
    const float*    __restrict__ rot,     // (B, 3, 3)
    const float*    __restrict__ coord,   // (P, 2)
    const int*      __restrict__ max_r,
    float*          __restrict__ out,     // (B, P, 2)
    int P)
{
    const int m    = blockIdx.x;
    const int xcd  = m & 7;                    // XCD-aware batch striping
    const int slot = m >> 3;
    const int b    = (slot / NBP2) * 8 + xcd;
    const int tid  = threadIdx.x;
    const int q    = tid & 3;                  // quad lane
    const int h    = q & 1;                    // input half
    const int dxl  = q >> 1;                   // this lane's corner dx
    const int pid  = tid >> 2;                 // [0,128)
    const int pA   = (slot % NBP2) * 256 + pid;        // always < P (12927 max)
    const int pB   = pA + 128;
    const bool inB = (pB < P);

    const int   mr  = min(max_r[0], (BZ - 6) / 2);
    const float mr2 = (float)(mr * mr);

    // ---- validity (cheap) + wave-uniform early-out ----
    const float2 xyA = *(const float2*)(coord + 2 * pA);
    const int    pBl = inB ? pB : (P - 1);
    const float2 xyB = *(const float2*)(coord + 2 * pBl);
    const bool validA = (xyA.x * xyA.x + xyA.y * xyA.y) <= mr2;
    const bool validB = inB && ((xyB.x * xyB.x + xyB.y * xyB.y) <= mr2);

    float* ob = out + ((size_t)b * P) * 2;
    if (!__any((int)(validA || validB))) {
        if (q == 0) {
            *(float2*)(ob + 2 * pA) = make_float2(0.f, 0.f);
            if (inB) *(float2*)(ob + 2 * pB) = make_float2(0.f, 0.f);
        }
        return;
    }

    const float* R = rot + b * 9;              // block-uniform -> scalar loads
    const float R0 = R[0], R1 = R[1], R3 = R[3];
    const float R4 = R[4], R6 = R[6], R7 = R[7];

    // shared across A and B: this lane's half of input[b] (16B aligned)
    const float4 ih = *(const float4*)(input + b * 8 + h * 4);

    const int SY = NX;                         // +dy stride (cells)
    const int SZ = NX * BZ;                    // +dz stride (cells)

    // ================= point A setup + garr issue =================
    float cxA = validA ? fmaf(R1, xyA.y, R0 * xyA.x) : 0.f;
    float cyA = validA ? fmaf(R4, xyA.y, R3 * xyA.x) : 0.f;
    float czA = validA ? fmaf(R7, xyA.y, R6 * xyA.x) : 0.f;
    float sgnA = 1.f;
    if (cxA < 0.f) { cxA = -cxA; cyA = -cyA; czA = -czA; sgnA = -1.f; }
    const float fxA = floorf(cxA), fyA = floorf(cyA), fzA = floorf(czA);
    const float txA = cxA - fxA, tyA = cyA - fyA, tzA = czA - fzA;
    const int baseA = (((int)fzA + BZ2) * BZ + ((int)fyA + BZ2)) * NX
                    + (int)fxA + dxl;
    int2 GlA[4];                               // i = dz*2 + dy
    GlA[0] = garr[baseA];
    GlA[1] = garr[baseA + SY];
    GlA[2] = garr[baseA + SZ];
    GlA[3] = garr[baseA + SZ + SY];

    // ================= point B setup + garr issue =================
    float cxB = validB ? fmaf(R1, xyB.y, R0 * xyB.x) : 0.f;
    float cyB = validB ? fmaf(R4, xyB.y, R3 * xyB.x) : 0.f;
    float czB = validB ? fmaf(R7, xyB.y, R6 * xyB.x) : 0.f;
    float sgnB = 1.f;
    if (cxB < 0.f) { cxB = -cxB; cyB = -cyB; czB = -czB; sgnB = -1.f; }
    const float fxB = floorf(cxB), fyB = floorf(cyB), fzB = floorf(czB);
    const float txB = cxB - fxB, tyB = cyB - fyB, tzB = czB - fzB;
    const int baseB = (((int)fzB + BZ2) * BZ + ((int)fyB + BZ2)) * NX
                    + (int)fxB + dxl;
    int2 GlB[4];
    GlB[0] = garr[baseB];
    GlB[1] = garr[baseB + SY];
    GlB[2] = garr[baseB + SZ];
    GlB[3] = garr[baseB + SZ + SY];

    // ================= A: resolve j, issue wpk =================
    const float wxdA = dxl ? txA : 1.f - txA;
    float wyzA[4];
    wyzA[0] = (1.f - tyA) * (1.f - tzA);
    wyzA[1] = tyA * (1.f - tzA);
    wyzA[2] = (1.f - tyA) * tzA;
    wyzA[3] = tyA * tzA;
    float wclA[4]; unsigned bbA[4]; uint4 UA[4];
    #pragma unroll
    for (int i = 0; i < 4; ++i) {
        const int j = GlA[i].x;
        bbA[i]  = (unsigned)GlA[i].y;
        wclA[i] = (validA && j >= 0) ? wxdA * wyzA[i] : 0.f;
        UA[i] = *(const uint4*)(wpk + (size_t)max(j, 0) * 8 + h * 4);
    }

    // ================= B: resolve j, issue wpk =================
    const float wxdB = dxl ? txB : 1.f - txB;
    float wyzB[4];
    wyzB[0] = (1.f - tyB) * (1.f - tzB);
    wyzB[1] = tyB * (1.f - tzB);
    wyzB[2] = (1.f - tyB) * tzB;
    wyzB[3] = tyB * tzB;
    float wclB[4]; unsigned bbB[4]; uint4 UB[4];
    #pragma unroll
    for (int i = 0; i < 4; ++i) {
        const int j = GlB[i].x;
        bbB[i]  = (unsigned)GlB[i].y;
        wclB[i] = (validB && j >= 0) ? wxdB * wyzB[i] : 0.f;
        UB[i] = *(const uint4*)(wpk + (size_t)max(j, 0) * 8 + h * 4);
    }

    // ================= A: fma + quad-reduce + store =================
    {
        float acc0 = 0.f, acc1 = 0.f;
        #pragma unroll
        for (int i = 0; i < 4; ++i) {
            const float w = wclA[i];
            float v0 = h ? 0.f : bf_lo(bbA[i]);   // bias once per corner
            float v1 = h ? 0.f : bf_hi(bbA[i]);
            v0 = fmaf(ih.x, bf_lo(UA[i].x), v0); v1 = fmaf(ih.x, bf_hi(UA[i].x), v1);
            v0 = fmaf(ih.y, bf_lo(UA[i].y), v0); v1 = fmaf(ih.y, bf_hi(UA[i].y), v1);
            v0 = fmaf(ih.z, bf_lo(UA[i].z), v0); v1 = fmaf(ih.z, bf_hi(UA[i].z), v1);
            v0 = fmaf(ih.w, bf_lo(UA[i].w), v0); v1 = fmaf(ih.w, bf_hi(UA[i].w), v1);
            acc0 = fmaf(w, v0, acc0);
            acc1 = fmaf(w, v1, acc1);
        }
        acc0 += __shfl_xor(acc0, 1);
        acc1 += __shfl_xor(acc1, 1);
        acc0 += __shfl_xor(acc0, 2);
        acc1 += __shfl_xor(acc1, 2);
        if (q == 0) *(float2*)(ob + 2 * pA) = make_float2(acc0, acc1 * sgnA);
    }

    // ================= B: fma + quad-reduce + store =================
    {
        float acc0 = 0.f, acc1 = 0.f;
        #pragma unroll
        for (int i = 0; i < 4; ++i) {
            const float w = wclB[i];
            float v0 = h ? 0.f : bf_lo(bbB[i]);
            float v1 = h ? 0.f : bf_hi(bbB[i]);
            v0 = fmaf(ih.x, bf_lo(UB[i].x), v0); v1 = fmaf(ih.x, bf_hi(UB[i].x), v1);
            v0 = fmaf(ih.y, bf_lo(UB[i].y), v0); v1 = fmaf(ih.y, bf_hi(UB[i].y), v1);
            v0 = fmaf(ih.z, bf_lo(UB[i].z), v0); v1 = fmaf(ih.z, bf_hi(UB[i].z), v1);
            v0 = fmaf(ih.w, bf_lo(UB[i].w), v0); v1 = fmaf(ih.w, bf_hi(UB[i].w), v1);
            acc0 = fmaf(w, v0, acc0);
            acc1 = fmaf(w, v1, acc1);
        }
        acc0 += __shfl_xor(acc0, 1);
        acc1 += __shfl_xor(acc1, 1);
        acc0 += __shfl_xor(acc0, 2);
        acc1 += __shfl_xor(acc1, 2);
        if (q == 0 && inB) *(float2*)(ob + 2 * pB) = make_float2(acc0, acc1 * sgnB);
    }
}

// ============ fallback tier 2: bf16 weights + separate bias ==================
__global__ __launch_bounds__(256) void pack_w(
    const float4* __restrict__ src, uint2* __restrict__ dst, int n)
{
    const int i = blockIdx.x * 256 + threadIdx.x;
    if (i >= n) return;
    const float4 v = src[i];
    dst[i] = make_uint2(f2bf(v.x) | (f2bf(v.y) << 16),
                        f2bf(v.z) | (f2bf(v.w) << 16));
}
__global__ __launch_bounds__(256) void pack_b(
    const float* __restrict__ bias, unsigned* __restrict__ bpk, int W)
{
    const int j = blockIdx.x * 256 + threadIdx.x;
    if (j >= W) return;
    bpk[j] = f2bf(bias[2 * j]) | (f2bf(bias[2 * j + 1]) << 16);
}

__global__ __launch_bounds__(256) void svr_bf16(
    const float* __restrict__ input, const unsigned* __restrict__ wpk,
    const unsigned* __restrict__ bpk, const int* __restrict__ grid3d,
    const float* __restrict__ rot, const float* __restrict__ coord,
    const int* __restrict__ max_r, float* __restrict__ out, int P)
{
    const int m    = blockIdx.x;
    const int xcd  = m & 7;
    const int slot = m >> 3;
    const int b    = (slot / NBX) * 8 + xcd;
    const int p    = (slot % NBX) * 256 + threadIdx.x;
    if (p >= P) return;

    const float x = coord[2 * p + 0];
    const float y = coord[2 * p + 1];
    const int mr = min(max_r[0], (BZ - 6) / 2);
    const bool valid = (x * x + y * y) <= (float)(mr * mr);
    float2* o = (float2*)(out + ((size_t)b * P + p) * 2);
    if (!valid) { *o = make_float2(0.f, 0.f); return; }

    const float* R = rot + b * 9;
    float cx = fmaf(R[1], y, R[0] * x);
    float cy = fmaf(R[4], y, R[3] * x);
    float cz = fmaf(R[7], y, R[6] * x);
    float sgn = 1.f;
    if (cx < 0.f) { cx = -cx; cy = -cy; cz = -cz; sgn = -1.f; }
    const float fx = floorf(cx), fy = floorf(cy), fz = floorf(cz);
    const float tx = cx - fx, ty = cy - fy, tz = cz - fz;
    const int ix = (int)fx, iy = (int)fy + BZ2, iz = (int)fz + BZ2;

    const float* ib = input + b * 8;
    const float in0 = ib[0], in1 = ib[1], in2 = ib[2], in3 = ib[3];
    const float in4 = ib[4], in5 = ib[5], in6 = ib[6], in7 = ib[7];

    int jj[8]; float wc[8];
    const float wx0 = 1.f - tx, wy0 = 1.f - ty, wz0 = 1.f - tz;
    #pragma unroll
    for (int dz = 0; dz < 2; ++dz)
        #pragma unroll
        for (int dy = 0; dy < 2; ++dy) {
            const int base = ((iz + dz) * BZ + (iy + dy)) * NX + ix;
            #pragma unroll
            for (int dx = 0; dx < 2; ++dx) {
                const int c = dz * 4 + dy * 2 + dx;
                const int j = grid3d[base + dx];
                const float w = (dx ? tx : wx0) * (dy ? ty : wy0) * (dz ? tz : wz0);
                wc[c] = (j >= 0) ? w : 0.f;
                jj[c] = max(j, 0);
            }
        }

    uint4 U0[8], U1[8]; unsigned BB[8];
    #pragma unroll
    for (int c = 0; c < 8; ++c) {
        const uint4* wp = (const uint4*)(wpk + (size_t)jj[c] * 8);
        U0[c] = wp[0]; U1[c] = wp[1]; BB[c] = bpk[jj[c]];
    }

    float acc0 = 0.f, acc1 = 0.f;
    #pragma unroll
    for (int c = 0; c < 8; ++c) {
        const float w = wc[c];
        float v0 = bf_lo(BB[c]), v1 = bf_hi(BB[c]);
        v0 = fmaf(in0, bf_lo(U0[c].x), v0); v1 = fmaf(in0, bf_hi(U0[c].x), v1);
        v0 = fmaf(in1, bf_lo(U0[c].y), v0); v1 = fmaf(in1, bf_hi(U0[c].y), v1);
        v0 = fmaf(in2, bf_lo(U0[c].z), v0); v1 = fmaf(in2, bf_hi(U0[c].z), v1);
        v0 = fmaf(in3, bf_lo(U0[c].w), v0); v1 = fmaf(in3, bf_hi(U0[c].w), v1);
        v0 = fmaf(in4, bf_lo(U1[c].x), v0); v1 = fmaf(in4, bf_hi(U1[c].x), v1);
        v0 = fmaf(in5, bf_lo(U1[c].y), v0); v1 = fmaf(in5, bf_hi(U1[c].y), v1);
        v0 = fmaf(in6, bf_lo(U1[c].z), v0); v1 = fmaf(in6, bf_hi(U1[c].z), v1);
        v0 = fmaf(in7, bf_lo(U1[c].w), v0); v1 = fmaf(in7, bf_hi(U1[c].w), v1);
        acc0 = fmaf(w, v0, acc0);
        acc1 = fmaf(w, v1, acc1);
    }
    *o = make_float2(acc0, acc1 * sgn);
}

// ============ fallback tier 3: direct fp32 (no workspace needed) =============
__global__ __launch_bounds__(256) void svr_fp32(
    const float* __restrict__ input, const float* __restrict__ weight,
    const float* __restrict__ bias, const int* __restrict__ grid3d,
    const float* __restrict__ rot, const float* __restrict__ coord,
    const int* __restrict__ max_r, float* __restrict__ out, int P)
{
    const int m    = blockIdx.x;
    const int xcd  = m & 7;
    const int slot = m >> 3;
    const int b    = (slot / NBX) * 8 + xcd;
    const int p    = (slot % NBX) * 256 + threadIdx.x;
    if (p >= P) return;

    const float x = coord[2 * p + 0];
    const float y = coord[2 * p + 1];
    const int mr = min(max_r[0], (BZ - 6) / 2);
    const bool valid = (x * x + y * y) <= (float)(mr * mr);
    float2* o = (float2*)(out + ((size_t)b * P + p) * 2);
    if (!valid) { *o = make_float2(0.f, 0.f); return; }

    const float* R = rot + b * 9;
    float cx = fmaf(R[1], y, R[0] * x);
    float cy = fmaf(R[4], y, R[3] * x);
    float cz = fmaf(R[7], y, R[6] * x);
    float sgn = 1.f;
    if (cx < 0.f) { cx = -cx; cy = -cy; cz = -cz; sgn = -1.f; }
    const float fx = floorf(cx), fy = floorf(cy), fz = floorf(cz);
    const float tx = cx - fx, ty = cy - fy, tz = cz - fz;
    const int ix = (int)fx, iy = (int)fy + BZ2, iz = (int)fz + BZ2;

    const float* ib = input + b * 8;
    const float in0 = ib[0], in1 = ib[1], in2 = ib[2], in3 = ib[3];
    const float in4 = ib[4], in5 = ib[5], in6 = ib[6], in7 = ib[7];

    int jj[8]; float wc[8];
    const float wx0 = 1.f - tx, wy0 = 1.f - ty, wz0 = 1.f - tz;
    #pragma unroll
    for (int dz = 0; dz < 2; ++dz)
        #pragma unroll
        for (int dy = 0; dy < 2; ++dy) {
            const int base = ((iz + dz) * BZ + (iy + dy)) * NX + ix;
            #pragma unroll
            for (int dx = 0; dx < 2; ++dx) {
                const int c = dz * 4 + dy * 2 + dx;
                const int j = grid3d[base + dx];
                const float w = (dx ? tx : wx0) * (dy ? ty : wy0) * (dz ? tz : wz0);
                wc[c] = (j >= 0) ? w : 0.f;
                jj[c] = max(j, 0);
            }
        }

    float acc0 = 0.f, acc1 = 0.f;
    #pragma unroll
    for (int c = 0; c < 8; ++c) {
        const size_t j = (size_t)jj[c];
        const float4* wp = (const float4*)(weight + j * 16);
        const float4 W0 = wp[0], W1 = wp[1], W2 = wp[2], W3 = wp[3];
        const float2 bb = *(const float2*)(bias + j * 2);
        const float w = wc[c];
        float v0 = bb.x, v1 = bb.y;
        v0 = fmaf(in0, W0.x, v0); v1 = fmaf(in0, W0.y, v1);
        v0 = fmaf(in1, W0.z, v0); v1 = fmaf(in1, W0.w, v1);
        v0 = fmaf(in2, W1.x, v0); v1 = fmaf(in2, W1.y, v1);
        v0 = fmaf(in3, W1.z, v0); v1 = fmaf(in3, W1.w, v1);
        v0 = fmaf(in4, W2.x, v0); v1 = fmaf(in4, W2.y, v1);
        v0 = fmaf(in5, W2.z, v0); v1 = fmaf(in5, W2.w, v1);
        v0 = fmaf(in6, W3.x, v0); v1 = fmaf(in6, W3.y, v1);
        v0 = fmaf(in7, W3.z, v0); v1 = fmaf(in7, W3.w, v1);
        acc0 = fmaf(w, v0, acc0);
        acc1 = fmaf(w, v1, acc1);
    }
    *o = make_float2(acc0, acc1 * sgn);
}

extern "C" void kernel_launch(void* const* d_in, const int* in_sizes, int n_in,
                              void* d_out, int out_size, void* d_ws, size_t ws_size,
                              hipStream_t stream) {
    const float* input  = (const float*)d_in[0];
    const float* weight = (const float*)d_in[1];
    const float* bias   = (const float*)d_in[2];
    const int*   grid3d = (const int*)  d_in[3];
    const float* rot    = (const float*)d_in[4];
    const float* coord  = (const float*)d_in[5];
    const int*   max_r  = (const int*)  d_in[6];
    float* out = (float*)d_out;

    const int P = in_sizes[5] / 2;        // 13041
    const int B = in_sizes[4] / 9;        // 256
    const int W = in_sizes[1] / 16;       // weight_count

    const size_t wpk_bytes  = (size_t)W * 32;
    const size_t garr_bytes = (size_t)NCELL * 8;
    const size_t need_full  = wpk_bytes + garr_bytes;   // ~53 MB
    const size_t need_bf    = (size_t)W * 36;           // ~39 MB

    dim3 block(256, 1, 1);

    if (ws_size >= need_full) {
        unsigned* wpk = (unsigned*)d_ws;
        int2* garr = (int2*)((char*)d_ws + wpk_bytes);
        const int nw4 = W * 4;
        const int nbw = (nw4 + 255) / 256;
        const int nbg = (NCELL + 255) / 256;
        pack_all<<<nbw + nbg, block, 0, stream>>>(
            (const float4*)weight, (uint2*)wpk, nw4, nbw,
            grid3d, bias, garr, NCELL);
        dim3 grid(NBP2 * B, 1, 1);
        dim3 block2(512, 1, 1);
        svr_quad2<<<grid, block2, 0, stream>>>(input, wpk, garr, rot, coord,
                                               max_r, out, P);
    } else if (ws_size >= need_bf) {
        unsigned* wpk = (unsigned*)d_ws;
        unsigned* bpk = wpk + (size_t)W * 8;
        const int nw = W * 4;
        pack_w<<<(nw + 255) / 256, block, 0, stream>>>(
            (const float4*)weight, (uint2*)wpk, nw);
        pack_b<<<(W + 255) / 256, block, 0, stream>>>(bias, bpk, W);
        dim3 grid(NBX * B, 1, 1);
        svr_bf16<<<grid, block, 0, stream>>>(input, wpk, bpk, grid3d, rot,
                                             coord, max_r, out, P);
    } else {
        dim3 grid(NBX * B, 1, 1);
        svr_fp32<<<grid, block, 0, stream>>>(input, weight, bias, grid3d, rot,
                                             coord, max_r, out, P);
    }
}

// Round 4
// 225.358 us; speedup vs baseline: 1.0388x; 1.0388x over previous
//
#include <hip/hip_runtime.h>

#define BZ    167              // grid3d_index dims 0/1 (SIZE + 2*MARGIN)
#define BZ2   83               // BZ/2
#define NX    84               // BZ/2 + 1  (last axis)
#define NCELL (BZ * BZ * NX)   // 2,342,676 cells
#define SYC   NX               // +dy stride in cells
#define SZC   (NX * BZ)        // +dz stride in cells
#define NBX   51               // ceil(13041/256) blocks/batch (fallback tiers)
#define NBQ   204              // ceil(13041/64)  blocks/batch (quarter-lane)

// ---- bf16 helpers (round-to-nearest-even pack, free unpack) ----
static __device__ __forceinline__ unsigned f2bf(float f) {
    unsigned u = __float_as_uint(f);
    return (u + 0x7FFFu + ((u >> 16) & 1u)) >> 16;
}
static __device__ __forceinline__ float bf_lo(unsigned u) {
    return __uint_as_float(u << 16);
}
static __device__ __forceinline__ float bf_hi(unsigned u) {
    return __uint_as_float(u & 0xFFFF0000u);
}

// ---- fused pre-pass: pack weights fp32->bf16 AND build the z-paired dense
// metadata array garrD[cell] = (j,bias)@cell || (j,bias)@(cell+SZ).  The
// z-duplication lets the main kernel fetch all 4 (dy,dz) metadata corners in
// TWO int4 gathers instead of four int2 gathers — the main kernel is bound by
// distinct-line touches per point (R0-R3: dur pinned ~100us while traffic,
// VALU, chains all varied), so halving metadata touches is the lever. ----
__global__ __launch_bounds__(256) void pack_allz(
    const float4* __restrict__ wsrc, uint2* __restrict__ wdst, int nw4, int nbw,
    const int* __restrict__ grid, const float* __restrict__ bias,
    int4* __restrict__ garrD, int ncell)
{
    if ((int)blockIdx.x < nbw) {
        const int i = blockIdx.x * 256 + threadIdx.x;
        if (i >= nw4) return;
        const float4 v = wsrc[i];
        wdst[i] = make_uint2(f2bf(v.x) | (f2bf(v.y) << 16),
                             f2bf(v.z) | (f2bf(v.w) << 16));
    } else {
        const int i = ((int)blockIdx.x - nbw) * 256 + threadIdx.x;
        if (i >= ncell) return;
        const int j0 = grid[i];
        const int j1 = (i + SZC < ncell) ? grid[i + SZC] : -1;
        unsigned b0 = 0u, b1 = 0u;
        if (j0 >= 0)
            b0 = f2bf(bias[2 * j0]) | (f2bf(bias[2 * j0 + 1]) << 16);
        if (j1 >= 0)
            b1 = f2bf(bias[2 * j1]) | (f2bf(bias[2 * j1 + 1]) << 16);
        garrD[i] = make_int4(j0, (int)b0, j1, (int)b1);
    }
}

// ========= main kernel: quarter-lane, z-paired metadata ======================
// Lane quad bits: bit0 = input half h (dims 4h..4h+3), bit1 = corner dx
// (folded into the garrD/wpk addresses).  Per point:
//   2 garrD int4 gathers  -> all 8 corners' (j,bias)   [was 4]
//   4 wpk   uint4 gathers -> 64B x-adjacent record pair per corner pair
// => ~6 distinct-line touches per point (was ~8).
__global__ __launch_bounds__(256, 4) void svr_quadz(
    const float*    __restrict__ input,   // (B, 8)
    const unsigned* __restrict__ wpk,     // (W, 8) uints = 16 bf16
    const int4*     __restrict__ garrD,   // (NCELL): z-paired (j, bias)
    const float*    __restrict__ rot,     // (B, 3, 3)
    const float*    __restrict__ coord,   // (P, 2)
    const int*      __restrict__ max_r,
    float*          __restrict__ out,     // (B, P, 2)
    int P)
{
    const int m    = blockIdx.x;
    const int xcd  = m & 7;                    // XCD-aware batch striping
    const int slot = m >> 3;
    const int b    = (slot / NBQ) * 8 + xcd;
    const int lane = threadIdx.x;
    const int q    = lane & 3;                 // quad lane
    const int h    = q & 1;                    // input half
    const int dxl  = q >> 1;                   // this lane's corner dx
    const int p    = (slot % NBQ) * 64 + (lane >> 2);
    if (p >= P) return;

    const float2 xy = *(const float2*)(coord + 2 * p);
    const float x = xy.x, y = xy.y;

    const int mr = min(max_r[0], (BZ - 6) / 2);
    const bool valid = (x * x + y * y) <= (float)(mr * mr);

    float2* o = (float2*)(out + ((size_t)b * P + p) * 2);
    if (!valid) {
        if (q == 0) *o = make_float2(0.f, 0.f);
        return;
    }

    const float* R = rot + b * 9;
    float cx = fmaf(R[1], y, R[0] * x);
    float cy = fmaf(R[4], y, R[3] * x);
    float cz = fmaf(R[7], y, R[6] * x);

    float sgn = 1.f;
    if (cx < 0.f) { cx = -cx; cy = -cy; cz = -cz; sgn = -1.f; }

    const float fx = floorf(cx), fy = floorf(cy), fz = floorf(cz);
    const float tx = cx - fx, ty = cy - fy, tz = cz - fz;
    const int ix = (int)fx;
    const int iy = (int)fy + BZ2;
    const int iz = (int)fz + BZ2;

    // ---- 2 z-paired metadata gathers (dx folded into address) ----
    const int base0 = (iz * BZ + iy) * NX + ix + dxl;
    const int4 Gd0 = garrD[base0];         // .xy=(dy0,dz0)  .zw=(dy0,dz1)
    const int4 Gd1 = garrD[base0 + SYC];   // .xy=(dy1,dz0)  .zw=(dy1,dz1)

    // this lane's half of input[b] (16B aligned)
    const float4 ih = *(const float4*)(input + b * 8 + h * 4);

    // per-lane corner weights: fixed dx factor x per-i (dy,dz) factor
    const float wxd = dxl ? tx : 1.f - tx;
    float wyz[4];                               // i: 0=(dy0,dz0) 1=(dy1,dz0)
    wyz[0] = (1.f - ty) * (1.f - tz);           //    2=(dy0,dz1) 3=(dy1,dz1)
    wyz[1] = ty * (1.f - tz);
    wyz[2] = (1.f - ty) * tz;
    wyz[3] = ty * tz;

    int jraw[4]; unsigned bbl[4];
    jraw[0] = Gd0.x; bbl[0] = (unsigned)Gd0.y;
    jraw[1] = Gd1.x; bbl[1] = (unsigned)Gd1.y;
    jraw[2] = Gd0.z; bbl[2] = (unsigned)Gd0.w;
    jraw[3] = Gd1.z; bbl[3] = (unsigned)Gd1.w;

    int jj[4]; float wcl[4];
    #pragma unroll
    for (int i = 0; i < 4; ++i) {
        wcl[i] = (jraw[i] >= 0) ? wxd * wyz[i] : 0.f;
        jj[i]  = max(jraw[i], 0);
    }

    // ---- 4 record gathers: lane quad covers the 64B x-adjacent record pair
    uint4 U[4];
    #pragma unroll
    for (int i = 0; i < 4; ++i)
        U[i] = *(const uint4*)(wpk + (size_t)jj[i] * 8 + h * 4);

    float acc0 = 0.f, acc1 = 0.f;
    #pragma unroll
    for (int i = 0; i < 4; ++i) {
        const float w = wcl[i];
        const unsigned bb = bbl[i];
        // bias contributes once per corner: h==0 lane only
        float v0 = h ? 0.f : bf_lo(bb);
        float v1 = h ? 0.f : bf_hi(bb);
        v0 = fmaf(ih.x, bf_lo(U[i].x), v0); v1 = fmaf(ih.x, bf_hi(U[i].x), v1);
        v0 = fmaf(ih.y, bf_lo(U[i].y), v0); v1 = fmaf(ih.y, bf_hi(U[i].y), v1);
        v0 = fmaf(ih.z, bf_lo(U[i].z), v0); v1 = fmaf(ih.z, bf_hi(U[i].z), v1);
        v0 = fmaf(ih.w, bf_lo(U[i].w), v0); v1 = fmaf(ih.w, bf_hi(U[i].w), v1);
        acc0 = fmaf(w, v0, acc0);
        acc1 = fmaf(w, v1, acc1);
    }

    // combine input halves (xor 1) then dx halves (xor 2) within the quad
    acc0 += __shfl_xor(acc0, 1);
    acc1 += __shfl_xor(acc1, 1);
    acc0 += __shfl_xor(acc0, 2);
    acc1 += __shfl_xor(acc1, 2);

    if (q == 0) *o = make_float2(acc0, acc1 * sgn);
}

// ============ fallback tier 2: bf16 weights + separate bias ==================
__global__ __launch_bounds__(256) void pack_w(
    const float4* __restrict__ src, uint2* __restrict__ dst, int n)
{
    const int i = blockIdx.x * 256 + threadIdx.x;
    if (i >= n) return;
    const float4 v = src[i];
    dst[i] = make_uint2(f2bf(v.x) | (f2bf(v.y) << 16),
                        f2bf(v.z) | (f2bf(v.w) << 16));
}
__global__ __launch_bounds__(256) void pack_b(
    const float* __restrict__ bias, unsigned* __restrict__ bpk, int W)
{
    const int j = blockIdx.x * 256 + threadIdx.x;
    if (j >= W) return;
    bpk[j] = f2bf(bias[2 * j]) | (f2bf(bias[2 * j + 1]) << 16);
}

__global__ __launch_bounds__(256) void svr_bf16(
    const float* __restrict__ input, const unsigned* __restrict__ wpk,
    const unsigned* __restrict__ bpk, const int* __restrict__ grid3d,
    const float* __restrict__ rot, const float* __restrict__ coord,
    const int* __restrict__ max_r, float* __restrict__ out, int P)
{
    const int m    = blockIdx.x;
    const int xcd  = m & 7;
    const int slot = m >> 3;
    const int b    = (slot / NBX) * 8 + xcd;
    const int p    = (slot % NBX) * 256 + threadIdx.x;
    if (p >= P) return;

    const float x = coord[2 * p + 0];
    const float y = coord[2 * p + 1];
    const int mr = min(max_r[0], (BZ - 6) / 2);
    const bool valid = (x * x + y * y) <= (float)(mr * mr);
    float2* o = (float2*)(out + ((size_t)b * P + p) * 2);
    if (!valid) { *o = make_float2(0.f, 0.f); return; }

    const float* R = rot + b * 9;
    float cx = fmaf(R[1], y, R[0] * x);
    float cy = fmaf(R[4], y, R[3] * x);
    float cz = fmaf(R[7], y, R[6] * x);
    float sgn = 1.f;
    if (cx < 0.f) { cx = -cx; cy = -cy; cz = -cz; sgn = -1.f; }
    const float fx = floorf(cx), fy = floorf(cy), fz = floorf(cz);
    const float tx = cx - fx, ty = cy - fy, tz = cz - fz;
    const int ix = (int)fx, iy = (int)fy + BZ2, iz = (int)fz + BZ2;

    const float* ib = input + b * 8;
    const float in0 = ib[0], in1 = ib[1], in2 = ib[2], in3 = ib[3];
    const float in4 = ib[4], in5 = ib[5], in6 = ib[6], in7 = ib[7];

    int jj[8]; float wc[8];
    const float wx0 = 1.f - tx, wy0 = 1.f - ty, wz0 = 1.f - tz;
    #pragma unroll
    for (int dz = 0; dz < 2; ++dz)
        #pragma unroll
        for (int dy = 0; dy < 2; ++dy) {
            const int base = ((iz + dz) * BZ + (iy + dy)) * NX + ix;
            #pragma unroll
            for (int dx = 0; dx < 2; ++dx) {
                const int c = dz * 4 + dy * 2 + dx;
                const int j = grid3d[base + dx];
                const float w = (dx ? tx : wx0) * (dy ? ty : wy0) * (dz ? tz : wz0);
                wc[c] = (j >= 0) ? w : 0.f;
                jj[c] = max(j, 0);
            }
        }

    uint4 U0[8], U1[8]; unsigned BB[8];
    #pragma unroll
    for (int c = 0; c < 8; ++c) {
        const uint4* wp = (const uint4*)(wpk + (size_t)jj[c] * 8);
        U0[c] = wp[0]; U1[c] = wp[1]; BB[c] = bpk[jj[c]];
    }

    float acc0 = 0.f, acc1 = 0.f;
    #pragma unroll
    for (int c = 0; c < 8; ++c) {
        const float w = wc[c];
        float v0 = bf_lo(BB[c]), v1 = bf_hi(BB[c]);
        v0 = fmaf(in0, bf_lo(U0[c].x), v0); v1 = fmaf(in0, bf_hi(U0[c].x), v1);
        v0 = fmaf(in1, bf_lo(U0[c].y), v0); v1 = fmaf(in1, bf_hi(U0[c].y), v1);
        v0 = fmaf(in2, bf_lo(U0[c].z), v0); v1 = fmaf(in2, bf_hi(U0[c].z), v1);
        v0 = fmaf(in3, bf_lo(U0[c].w), v0); v1 = fmaf(in3, bf_hi(U0[c].w), v1);
        v0 = fmaf(in4, bf_lo(U1[c].x), v0); v1 = fmaf(in4, bf_hi(U1[c].x), v1);
        v0 = fmaf(in5, bf_lo(U1[c].y), v0); v1 = fmaf(in5, bf_hi(U1[c].y), v1);
        v0 = fmaf(in6, bf_lo(U1[c].z), v0); v1 = fmaf(in6, bf_hi(U1[c].z), v1);
        v0 = fmaf(in7, bf_lo(U1[c].w), v0); v1 = fmaf(in7, bf_hi(U1[c].w), v1);
        acc0 = fmaf(w, v0, acc0);
        acc1 = fmaf(w, v1, acc1);
    }
    *o = make_float2(acc0, acc1 * sgn);
}

// ============ fallback tier 3: direct fp32 (no workspace needed) =============
__global__ __launch_bounds__(256) void svr_fp32(
    const float* __restrict__ input, const float* __restrict__ weight,
    const float* __restrict__ bias, const int* __restrict__ grid3d,
    const float* __restrict__ rot, const float* __restrict__ coord,
    const int* __restrict__ max_r, float* __restrict__ out, int P)
{
    const int m    = blockIdx.x;
    const int xcd  = m & 7;
    const int slot = m >> 3;
    const int b    = (slot / NBX) * 8 + xcd;
    const int p    = (slot % NBX) * 256 + threadIdx.x;
    if (p >= P) return;

    const float x = coord[2 * p + 0];
    const float y = coord[2 * p + 1];
    const int mr = min(max_r[0], (BZ - 6) / 2);
    const bool valid = (x * x + y * y) <= (float)(mr * mr);
    float2* o = (float2*)(out + ((size_t)b * P + p) * 2);
    if (!valid) { *o = make_float2(0.f, 0.f); return; }

    const float* R = rot + b * 9;
    float cx = fmaf(R[1], y, R[0] * x);
    float cy = fmaf(R[4], y, R[3] * x);
    float cz = fmaf(R[7], y, R[6] * x);
    float sgn = 1.f;
    if (cx < 0.f) { cx = -cx; cy = -cy; cz = -cz; sgn = -1.f; }
    const float fx = floorf(cx), fy = floorf(cy), fz = floorf(cz);
    const float tx = cx - fx, ty = cy - fy, tz = cz - fz;
    const int ix = (int)fx, iy = (int)fy + BZ2, iz = (int)fz + BZ2;

    const float* ib = input + b * 8;
    const float in0 = ib[0], in1 = ib[1], in2 = ib[2], in3 = ib[3];
    const float in4 = ib[4], in5 = ib[5], in6 = ib[6], in7 = ib[7];

    int jj[8]; float wc[8];
    const float wx0 = 1.f - tx, wy0 = 1.f - ty, wz0 = 1.f - tz;
    #pragma unroll
    for (int dz = 0; dz < 2; ++dz)
        #pragma unroll
        for (int dy = 0; dy < 2; ++dy) {
            const int base = ((iz + dz) * BZ + (iy + dy)) * NX + ix;
            #pragma unroll
            for (int dx = 0; dx < 2; ++dx) {
                const int c = dz * 4 + dy * 2 + dx;
                const int j = grid3d[base + dx];
                const float w = (dx ? tx : wx0) * (dy ? ty : wy0) * (dz ? tz : wz0);
                wc[c] = (j >= 0) ? w : 0.f;
                jj[c] = max(j, 0);
            }
        }

    float acc0 = 0.f, acc1 = 0.f;
    #pragma unroll
    for (int c = 0; c < 8; ++c) {
        const size_t j = (size_t)jj[c];
        const float4* wp = (const float4*)(weight + j * 16);
        const float4 W0 = wp[0], W1 = wp[1], W2 = wp[2], W3 = wp[3];
        const float2 bb = *(const float2*)(bias + j * 2);
        const float w = wc[c];
        float v0 = bb.x, v1 = bb.y;
        v0 = fmaf(in0, W0.x, v0); v1 = fmaf(in0, W0.y, v1);
        v0 = fmaf(in1, W0.z, v0); v1 = fmaf(in1, W0.w, v1);
        v0 = fmaf(in2, W1.x, v0); v1 = fmaf(in2, W1.y, v1);
        v0 = fmaf(in3, W1.z, v0); v1 = fmaf(in3, W1.w, v1);
        v0 = fmaf(in4, W2.x, v0); v1 = fmaf(in4, W2.y, v1);
        v0 = fmaf(in5, W2.z, v0); v1 = fmaf(in5, W2.w, v1);
        v0 = fmaf(in6, W3.x, v0); v1 = fmaf(in6, W3.y, v1);
        v0 = fmaf(in7, W3.z, v0); v1 = fmaf(in7, W3.w, v1);
        acc0 = fmaf(w, v0, acc0);
        acc1 = fmaf(w, v1, acc1);
    }
    *o = make_float2(acc0, acc1 * sgn);
}

extern "C" void kernel_launch(void* const* d_in, const int* in_sizes, int n_in,
                              void* d_out, int out_size, void* d_ws, size_t ws_size,
                              hipStream_t stream) {
    const float* input  = (const float*)d_in[0];
    const float* weight = (const float*)d_in[1];
    const float* bias   = (const float*)d_in[2];
    const int*   grid3d = (const int*)  d_in[3];
    const float* rot    = (const float*)d_in[4];
    const float* coord  = (const float*)d_in[5];
    const int*   max_r  = (const int*)  d_in[6];
    float* out = (float*)d_out;

    const int P = in_sizes[5] / 2;        // 13041
    const int B = in_sizes[4] / 9;        // 256
    const int W = in_sizes[1] / 16;       // weight_count

    const size_t wpk_bytes = (size_t)W * 32;
    const size_t need_zd   = wpk_bytes + (size_t)NCELL * 16;  // ~72 MB (fits:
                                                              // R0 ran this size)
    const size_t need_bf   = (size_t)W * 36;                  // ~39 MB

    dim3 block(256, 1, 1);

    if (ws_size >= need_zd) {
        unsigned* wpk = (unsigned*)d_ws;
        int4* garrD = (int4*)((char*)d_ws + wpk_bytes);
        const int nw4 = W * 4;
        const int nbw = (nw4 + 255) / 256;
        const int nbg = (NCELL + 255) / 256;
        pack_allz<<<nbw + nbg, block, 0, stream>>>(
            (const float4*)weight, (uint2*)wpk, nw4, nbw,
            grid3d, bias, garrD, NCELL);
        dim3 grid(NBQ * B, 1, 1);
        svr_quadz<<<grid, block, 0, stream>>>(input, wpk, garrD, rot, coord,
                                              max_r, out, P);
    } else if (ws_size >= need_bf) {
        unsigned* wpk = (unsigned*)d_ws;
        unsigned* bpk = wpk + (size_t)W * 8;
        const int nw = W * 4;
        pack_w<<<(nw + 255) / 256, block, 0, stream>>>(
            (const float4*)weight, (uint2*)wpk, nw);
        pack_b<<<(W + 255) / 256, block, 0, stream>>>(bias, bpk, W);
        dim3 grid(NBX * B, 1, 1);
        svr_bf16<<<grid, block, 0, stream>>>(input, wpk, bpk, grid3d, rot,
                                             coord, max_r, out, P);
    } else {
        dim3 grid(NBX * B, 1, 1);
        svr_fp32<<<grid, block, 0, stream>>>(input, weight, bias, grid3d, rot,
                                             coord, max_r, out, P);
    }
}

// Round 5
// 220.742 us; speedup vs baseline: 1.0605x; 1.0209x over previous
//
#include <hip/hip_runtime.h>

#define BZ    167              // grid3d_index dims 0/1 (SIZE + 2*MARGIN)
#define BZ2   83               // BZ/2
#define NX    84               // BZ/2 + 1  (last axis)
#define NCELL (BZ * BZ * NX)   // 2,342,676 cells
#define SYC   NX               // +dy stride in cells
#define SZC   (NX * BZ)        // +dz stride in cells
#define NXC   81               // 2D coord grid x extent (SIZE/2+1)
#define NYC   161              // 2D coord grid y extent (SIZE)
#define NTX   21               // ceil(81/4)  tiles in x
#define NTY   41               // ceil(161/4) tiles in y
#define NTILE (NTX * NTY)      // 861 4x4 tiles/batch
#define NBT   216              // ceil(861/4) blocks/batch (4 waves/block)
#define NBX   51               // ceil(13041/256) blocks/batch (fallback tiers)

// ---- bf16 helpers (round-to-nearest-even pack, free unpack) ----
static __device__ __forceinline__ unsigned f2bf(float f) {
    unsigned u = __float_as_uint(f);
    return (u + 0x7FFFu + ((u >> 16) & 1u)) >> 16;
}
static __device__ __forceinline__ float bf_lo(unsigned u) {
    return __uint_as_float(u << 16);
}
static __device__ __forceinline__ float bf_hi(unsigned u) {
    return __uint_as_float(u & 0xFFFF0000u);
}

// ---- fused pre-pass: pack weights fp32->bf16 AND build the z-paired dense
// metadata array garrD[cell] = (j,bias)@cell || (j,bias)@(cell+SZ) ----
__global__ __launch_bounds__(256) void pack_allz(
    const float4* __restrict__ wsrc, uint2* __restrict__ wdst, int nw4, int nbw,
    const int* __restrict__ grid, const float* __restrict__ bias,
    int4* __restrict__ garrD, int ncell)
{
    if ((int)blockIdx.x < nbw) {
        const int i = blockIdx.x * 256 + threadIdx.x;
        if (i >= nw4) return;
        const float4 v = wsrc[i];
        wdst[i] = make_uint2(f2bf(v.x) | (f2bf(v.y) << 16),
                             f2bf(v.z) | (f2bf(v.w) << 16));
    } else {
        const int i = ((int)blockIdx.x - nbw) * 256 + threadIdx.x;
        if (i >= ncell) return;
        const int j0 = grid[i];
        const int j1 = (i + SZC < ncell) ? grid[i + SZC] : -1;
        unsigned b0 = 0u, b1 = 0u;
        if (j0 >= 0)
            b0 = f2bf(bias[2 * j0]) | (f2bf(bias[2 * j0 + 1]) << 16);
        if (j1 >= 0)
            b1 = f2bf(bias[2 * j1]) | (f2bf(bias[2 * j1 + 1]) << 16);
        garrD[i] = make_int4(j0, (int)b0, j1, (int)b1);
    }
}

// ========= main kernel: quarter-lane, z-paired metadata, 4x4 WAVE TILES ======
// R0-R4 model: dur = distinct-cache-line touches per wave-instruction x ~3cyc
// (TA gather path).  With the old 1x16-run point mapping, line sharing inside
// a wave depends on the rotation's dominant axis (x-dominant: free; y/z:
// every point pays its own line).  Remapping each wave's 16 points to a 4x4
// tile of the 2D grid bounds the rotated 3D patch to diameter ~5.7 for ANY
// rotation -> gathers concentrate into few (z,y) rows / short j-ranges.
// Data structures and inner math unchanged from R4 (svr_quadz).
__global__ __launch_bounds__(256, 4) void svr_tile(
    const float*    __restrict__ input,   // (B, 8)
    const unsigned* __restrict__ wpk,     // (W, 8) uints = 16 bf16
    const int4*     __restrict__ garrD,   // (NCELL): z-paired (j, bias)
    const float*    __restrict__ rot,     // (B, 3, 3)
    const float*    __restrict__ coord,   // (P, 2)
    const int*      __restrict__ max_r,
    float*          __restrict__ out,     // (B, P, 2)
    int P)
{
    const int m    = blockIdx.x;
    const int xcd  = m & 7;                    // XCD-aware batch striping
    const int slot = m >> 3;
    const int b    = (slot / NBT) * 8 + xcd;
    const int tgrp = slot % NBT;
    const int wid  = threadIdx.x >> 6;         // wave in block (4 waves)
    const int lane = threadIdx.x & 63;
    const int t    = tgrp * 4 + wid;           // tile id
    if (t >= NTILE) return;

    const int q    = lane & 3;                 // quad lane
    const int h    = q & 1;                    // input half
    const int dxl  = q >> 1;                   // this lane's corner dx
    const int sub  = lane >> 2;                // point within tile [0,16)
    const int px   = (t % NTX) * 4 + (sub & 3);
    const int py   = (t / NTX) * 4 + (sub >> 2);
    if (px >= NXC || py >= NYC) return;        // out-of-grid: no store
    const int p    = py * NXC + px;

    const float2 xy = *(const float2*)(coord + 2 * p);
    const float x = xy.x, y = xy.y;

    const int mr = min(max_r[0], (BZ - 6) / 2);
    const bool valid = (x * x + y * y) <= (float)(mr * mr);

    float2* o = (float2*)(out + ((size_t)b * P + p) * 2);
    if (!valid) {
        if (q == 0) *o = make_float2(0.f, 0.f);
        return;
    }

    const float* R = rot + b * 9;
    float cx = fmaf(R[1], y, R[0] * x);
    float cy = fmaf(R[4], y, R[3] * x);
    float cz = fmaf(R[7], y, R[6] * x);

    float sgn = 1.f;
    if (cx < 0.f) { cx = -cx; cy = -cy; cz = -cz; sgn = -1.f; }

    const float fx = floorf(cx), fy = floorf(cy), fz = floorf(cz);
    const float tx = cx - fx, ty = cy - fy, tz = cz - fz;
    const int ix = (int)fx;
    const int iy = (int)fy + BZ2;
    const int iz = (int)fz + BZ2;

    // ---- 2 z-paired metadata gathers (dx folded into address) ----
    const int base0 = (iz * BZ + iy) * NX + ix + dxl;
    const int4 Gd0 = garrD[base0];         // .xy=(dy0,dz0)  .zw=(dy0,dz1)
    const int4 Gd1 = garrD[base0 + SYC];   // .xy=(dy1,dz0)  .zw=(dy1,dz1)

    // this lane's half of input[b] (16B aligned)
    const float4 ih = *(const float4*)(input + b * 8 + h * 4);

    // per-lane corner weights: fixed dx factor x per-i (dy,dz) factor
    const float wxd = dxl ? tx : 1.f - tx;
    float wyz[4];                               // i: 0=(dy0,dz0) 1=(dy1,dz0)
    wyz[0] = (1.f - ty) * (1.f - tz);           //    2=(dy0,dz1) 3=(dy1,dz1)
    wyz[1] = ty * (1.f - tz);
    wyz[2] = (1.f - ty) * tz;
    wyz[3] = ty * tz;

    int jraw[4]; unsigned bbl[4];
    jraw[0] = Gd0.x; bbl[0] = (unsigned)Gd0.y;
    jraw[1] = Gd1.x; bbl[1] = (unsigned)Gd1.y;
    jraw[2] = Gd0.z; bbl[2] = (unsigned)Gd0.w;
    jraw[3] = Gd1.z; bbl[3] = (unsigned)Gd1.w;

    int jj[4]; float wcl[4];
    #pragma unroll
    for (int i = 0; i < 4; ++i) {
        wcl[i] = (jraw[i] >= 0) ? wxd * wyz[i] : 0.f;
        jj[i]  = max(jraw[i], 0);
    }

    // ---- 4 record gathers: lane quad covers the 64B x-adjacent record pair
    uint4 U[4];
    #pragma unroll
    for (int i = 0; i < 4; ++i)
        U[i] = *(const uint4*)(wpk + (size_t)jj[i] * 8 + h * 4);

    float acc0 = 0.f, acc1 = 0.f;
    #pragma unroll
    for (int i = 0; i < 4; ++i) {
        const float w = wcl[i];
        const unsigned bb = bbl[i];
        // bias contributes once per corner: h==0 lane only
        float v0 = h ? 0.f : bf_lo(bb);
        float v1 = h ? 0.f : bf_hi(bb);
        v0 = fmaf(ih.x, bf_lo(U[i].x), v0); v1 = fmaf(ih.x, bf_hi(U[i].x), v1);
        v0 = fmaf(ih.y, bf_lo(U[i].y), v0); v1 = fmaf(ih.y, bf_hi(U[i].y), v1);
        v0 = fmaf(ih.z, bf_lo(U[i].z), v0); v1 = fmaf(ih.z, bf_hi(U[i].z), v1);
        v0 = fmaf(ih.w, bf_lo(U[i].w), v0); v1 = fmaf(ih.w, bf_hi(U[i].w), v1);
        acc0 = fmaf(w, v0, acc0);
        acc1 = fmaf(w, v1, acc1);
    }

    // combine input halves (xor 1) then dx halves (xor 2) within the quad
    acc0 += __shfl_xor(acc0, 1);
    acc1 += __shfl_xor(acc1, 1);
    acc0 += __shfl_xor(acc0, 2);
    acc1 += __shfl_xor(acc1, 2);

    if (q == 0) *o = make_float2(acc0, acc1 * sgn);
}

// ============ fallback tier 2: bf16 weights + separate bias ==================
__global__ __launch_bounds__(256) void pack_w(
    const float4* __restrict__ src, uint2* __restrict__ dst, int n)
{
    const int i = blockIdx.x * 256 + threadIdx.x;
    if (i >= n) return;
    const float4 v = src[i];
    dst[i] = make_uint2(f2bf(v.x) | (f2bf(v.y) << 16),
                        f2bf(v.z) | (f2bf(v.w) << 16));
}
__global__ __launch_bounds__(256) void pack_b(
    const float* __restrict__ bias, unsigned* __restrict__ bpk, int W)
{
    const int j = blockIdx.x * 256 + threadIdx.x;
    if (j >= W) return;
    bpk[j] = f2bf(bias[2 * j]) | (f2bf(bias[2 * j + 1]) << 16);
}

__global__ __launch_bounds__(256) void svr_bf16(
    const float* __restrict__ input, const unsigned* __restrict__ wpk,
    const unsigned* __restrict__ bpk, const int* __restrict__ grid3d,
    const float* __restrict__ rot, const float* __restrict__ coord,
    const int* __restrict__ max_r, float* __restrict__ out, int P)
{
    const int m    = blockIdx.x;
    const int xcd  = m & 7;
    const int slot = m >> 3;
    const int b    = (slot / NBX) * 8 + xcd;
    const int p    = (slot % NBX) * 256 + threadIdx.x;
    if (p >= P) return;

    const float x = coord[2 * p + 0];
    const float y = coord[2 * p + 1];
    const int mr = min(max_r[0], (BZ - 6) / 2);
    const bool valid = (x * x + y * y) <= (float)(mr * mr);
    float2* o = (float2*)(out + ((size_t)b * P + p) * 2);
    if (!valid) { *o = make_float2(0.f, 0.f); return; }

    const float* R = rot + b * 9;
    float cx = fmaf(R[1], y, R[0] * x);
    float cy = fmaf(R[4], y, R[3] * x);
    float cz = fmaf(R[7], y, R[6] * x);
    float sgn = 1.f;
    if (cx < 0.f) { cx = -cx; cy = -cy; cz = -cz; sgn = -1.f; }
    const float fx = floorf(cx), fy = floorf(cy), fz = floorf(cz);
    const float tx = cx - fx, ty = cy - fy, tz = cz - fz;
    const int ix = (int)fx, iy = (int)fy + BZ2, iz = (int)fz + BZ2;

    const float* ib = input + b * 8;
    const float in0 = ib[0], in1 = ib[1], in2 = ib[2], in3 = ib[3];
    const float in4 = ib[4], in5 = ib[5], in6 = ib[6], in7 = ib[7];

    int jj[8]; float wc[8];
    const float wx0 = 1.f - tx, wy0 = 1.f - ty, wz0 = 1.f - tz;
    #pragma unroll
    for (int dz = 0; dz < 2; ++dz)
        #pragma unroll
        for (int dy = 0; dy < 2; ++dy) {
            const int base = ((iz + dz) * BZ + (iy + dy)) * NX + ix;
            #pragma unroll
            for (int dx = 0; dx < 2; ++dx) {
                const int c = dz * 4 + dy * 2 + dx;
                const int j = grid3d[base + dx];
                const float w = (dx ? tx : wx0) * (dy ? ty : wy0) * (dz ? tz : wz0);
                wc[c] = (j >= 0) ? w : 0.f;
                jj[c] = max(j, 0);
            }
        }

    uint4 U0[8], U1[8]; unsigned BB[8];
    #pragma unroll
    for (int c = 0; c < 8; ++c) {
        const uint4* wp = (const uint4*)(wpk + (size_t)jj[c] * 8);
        U0[c] = wp[0]; U1[c] = wp[1]; BB[c] = bpk[jj[c]];
    }

    float acc0 = 0.f, acc1 = 0.f;
    #pragma unroll
    for (int c = 0; c < 8; ++c) {
        const float w = wc[c];
        float v0 = bf_lo(BB[c]), v1 = bf_hi(BB[c]);
        v0 = fmaf(in0, bf_lo(U0[c].x), v0); v1 = fmaf(in0, bf_hi(U0[c].x), v1);
        v0 = fmaf(in1, bf_lo(U0[c].y), v0); v1 = fmaf(in1, bf_hi(U0[c].y), v1);
        v0 = fmaf(in2, bf_lo(U0[c].z), v0); v1 = fmaf(in2, bf_hi(U0[c].z), v1);
        v0 = fmaf(in3, bf_lo(U0[c].w), v0); v1 = fmaf(in3, bf_hi(U0[c].w), v1);
        v0 = fmaf(in4, bf_lo(U1[c].x), v0); v1 = fmaf(in4, bf_hi(U1[c].x), v1);
        v0 = fmaf(in5, bf_lo(U1[c].y), v0); v1 = fmaf(in5, bf_hi(U1[c].y), v1);
        v0 = fmaf(in6, bf_lo(U1[c].z), v0); v1 = fmaf(in6, bf_hi(U1[c].z), v1);
        v0 = fmaf(in7, bf_lo(U1[c].w), v0); v1 = fmaf(in7, bf_hi(U1[c].w), v1);
        acc0 = fmaf(w, v0, acc0);
        acc1 = fmaf(w, v1, acc1);
    }
    *o = make_float2(acc0, acc1 * sgn);
}

// ============ fallback tier 3: direct fp32 (no workspace needed) =============
__global__ __launch_bounds__(256) void svr_fp32(
    const float* __restrict__ input, const float* __restrict__ weight,
    const float* __restrict__ bias, const int* __restrict__ grid3d,
    const float* __restrict__ rot, const float* __restrict__ coord,
    const int* __restrict__ max_r, float* __restrict__ out, int P)
{
    const int m    = blockIdx.x;
    const int xcd  = m & 7;
    const int slot = m >> 3;
    const int b    = (slot / NBX) * 8 + xcd;
    const int p    = (slot % NBX) * 256 + threadIdx.x;
    if (p >= P) return;

    const float x = coord[2 * p + 0];
    const float y = coord[2 * p + 1];
    const int mr = min(max_r[0], (BZ - 6) / 2);
    const bool valid = (x * x + y * y) <= (float)(mr * mr);
    float2* o = (float2*)(out + ((size_t)b * P + p) * 2);
    if (!valid) { *o = make_float2(0.f, 0.f); return; }

    const float* R = rot + b * 9;
    float cx = fmaf(R[1], y, R[0] * x);
    float cy = fmaf(R[4], y, R[3] * x);
    float cz = fmaf(R[7], y, R[6] * x);
    float sgn = 1.f;
    if (cx < 0.f) { cx = -cx; cy = -cy; cz = -cz; sgn = -1.f; }
    const float fx = floorf(cx), fy = floorf(cy), fz = floorf(cz);
    const float tx = cx - fx, ty = cy - fy, tz = cz - fz;
    const int ix = (int)fx, iy = (int)fy + BZ2, iz = (int)fz + BZ2;

    const float* ib = input + b * 8;
    const float in0 = ib[0], in1 = ib[1], in2 = ib[2], in3 = ib[3];
    const float in4 = ib[4], in5 = ib[5], in6 = ib[6], in7 = ib[7];

    int jj[8]; float wc[8];
    const float wx0 = 1.f - tx, wy0 = 1.f - ty, wz0 = 1.f - tz;
    #pragma unroll
    for (int dz = 0; dz < 2; ++dz)
        #pragma unroll
        for (int dy = 0; dy < 2; ++dy) {
            const int base = ((iz + dz) * BZ + (iy + dy)) * NX + ix;
            #pragma unroll
            for (int dx = 0; dx < 2; ++dx) {
                const int c = dz * 4 + dy * 2 + dx;
                const int j = grid3d[base + dx];
                const float w = (dx ? tx : wx0) * (dy ? ty : wy0) * (dz ? tz : wz0);
                wc[c] = (j >= 0) ? w : 0.f;
                jj[c] = max(j, 0);
            }
        }

    float acc0 = 0.f, acc1 = 0.f;
    #pragma unroll
    for (int c = 0; c < 8; ++c) {
        const size_t j = (size_t)jj[c];
        const float4* wp = (const float4*)(weight + j * 16);
        const float4 W0 = wp[0], W1 = wp[1], W2 = wp[2], W3 = wp[3];
        const float2 bb = *(const float2*)(bias + j * 2);
        const float w = wc[c];
        float v0 = bb.x, v1 = bb.y;
        v0 = fmaf(in0, W0.x, v0); v1 = fmaf(in0, W0.y, v1);
        v0 = fmaf(in1, W0.z, v0); v1 = fmaf(in1, W0.w, v1);
        v0 = fmaf(in2, W1.x, v0); v1 = fmaf(in2, W1.y, v1);
        v0 = fmaf(in3, W1.z, v0); v1 = fmaf(in3, W1.w, v1);
        v0 = fmaf(in4, W2.x, v0); v1 = fmaf(in4, W2.y, v1);
        v0 = fmaf(in5, W2.z, v0); v1 = fmaf(in5, W2.w, v1);
        v0 = fmaf(in6, W3.x, v0); v1 = fmaf(in6, W3.y, v1);
        v0 = fmaf(in7, W3.z, v0); v1 = fmaf(in7, W3.w, v1);
        acc0 = fmaf(w, v0, acc0);
        acc1 = fmaf(w, v1, acc1);
    }
    *o = make_float2(acc0, acc1 * sgn);
}

extern "C" void kernel_launch(void* const* d_in, const int* in_sizes, int n_in,
                              void* d_out, int out_size, void* d_ws, size_t ws_size,
                              hipStream_t stream) {
    const float* input  = (const float*)d_in[0];
    const float* weight = (const float*)d_in[1];
    const float* bias   = (const float*)d_in[2];
    const int*   grid3d = (const int*)  d_in[3];
    const float* rot    = (const float*)d_in[4];
    const float* coord  = (const float*)d_in[5];
    const int*   max_r  = (const int*)  d_in[6];
    float* out = (float*)d_out;

    const int P = in_sizes[5] / 2;        // 13041
    const int B = in_sizes[4] / 9;        // 256
    const int W = in_sizes[1] / 16;       // weight_count

    const size_t wpk_bytes = (size_t)W * 32;
    const size_t need_zd   = wpk_bytes + (size_t)NCELL * 16;  // ~72 MB
    const size_t need_bf   = (size_t)W * 36;                  // ~39 MB

    dim3 block(256, 1, 1);

    if (ws_size >= need_zd) {
        unsigned* wpk = (unsigned*)d_ws;
        int4* garrD = (int4*)((char*)d_ws + wpk_bytes);
        const int nw4 = W * 4;
        const int nbw = (nw4 + 255) / 256;
        const int nbg = (NCELL + 255) / 256;
        pack_allz<<<nbw + nbg, block, 0, stream>>>(
            (const float4*)weight, (uint2*)wpk, nw4, nbw,
            grid3d, bias, garrD, NCELL);
        dim3 grid(NBT * B, 1, 1);
        svr_tile<<<grid, block, 0, stream>>>(input, wpk, garrD, rot, coord,
                                             max_r, out, P);
    } else if (ws_size >= need_bf) {
        unsigned* wpk = (unsigned*)d_ws;
        unsigned* bpk = wpk + (size_t)W * 8;
        const int nw = W * 4;
        pack_w<<<(nw + 255) / 256, block, 0, stream>>>(
            (const float4*)weight, (uint2*)wpk, nw);
        pack_b<<<(W + 255) / 256, block, 0, stream>>>(bias, bpk, W);
        dim3 grid(NBX * B, 1, 1);
        svr_bf16<<<grid, block, 0, stream>>>(input, wpk, bpk, grid3d, rot,
                                             coord, max_r, out, P);
    } else {
        dim3 grid(NBX * B, 1, 1);
        svr_fp32<<<grid, block, 0, stream>>>(input, weight, bias, grid3d, rot,
                                             coord, max_r, out, P);
    }
}